// Round 12
// baseline (36.934 us; speedup 1.0000x reference)
//
#include <hip/hip_runtime.h>
#include <hip/hip_bf16.h>
#include <math.h>

#define D 256
#define NPROTO 1024
#define NROWS 16384
#define WRr 13
#define WCc 18
#define WJ (WRr * WCc)
#define JSUB 59                    // ceil(WJ/4)
#define GMAT_BLOCKS (NPROTO / 4)   // 256

typedef __attribute__((ext_vector_type(8))) short short8;
typedef __attribute__((ext_vector_type(4))) float f32x4;

__device__ __forceinline__ short f2bf(float f) {
    union { __hip_bfloat16 b; short s; } u;
    u.b = __float2bfloat16(f);
    return u.s;
}

__device__ __forceinline__ void gload_lds16(void* lds, const void* g) {
    __builtin_amdgcn_global_load_lds(
        (const __attribute__((address_space(1))) unsigned*)g,
        (__attribute__((address_space(3))) unsigned*)lds, 16, 0, 0);
}

// ---- hex-grid neighborhood H[i,j] on the fly (fp64, matches np ref) ----
__device__ __forceinline__ void proto_pos(int idx, double& x, double& y) {
    int r = idx >> 5, c = idx & 31;
    x = (double)c + 0.5 * (double)(r & 1);
    y = (double)r * 0.86602540378443864676;  // sqrt(3)/2
}

__device__ __forceinline__ float hval(int i, int j) {
    double xi, yi, xj, yj;
    proto_pos(i, xi, yi);
    proto_pos(j, xj, yj);
    double dx0 = xi - xj, dy0 = yi - yj;
    const double W = 32.0;
    const double Hh = 27.712812921102035;  // 32*sqrt(3)/2
    double best = 1e300;
#pragma unroll
    for (int sx = -1; sx <= 1; ++sx) {
        double dx = dx0 + (double)sx * W;
#pragma unroll
        for (int sy = -1; sy <= 1; ++sy) {
            double dy = dy0 + (double)sy * Hh;
            double d2 = dx * dx + dy * dy;
            best = fmin(best, d2);
        }
    }
    return (float)exp(-0.5 * best);
}

// GbS layout (kt-major, slot-swizzled; PROVEN in R10), k = kt*32 + slot*8 + e:
//  GbS short idx = kt*(NPROTO*32) + i*32 + ((slot ^ key(i))*8) + e
//  key(i) = (i&3)^((i>>2)&3)

// ---- prep: gmat only (256 blocks, 4 protos each) + out init ----
__global__ void __launch_bounds__(256) prep_kernel(
    const float* __restrict__ P, short* __restrict__ GbS,
    float* __restrict__ hsum, float* __restrict__ hp2,
    unsigned* __restrict__ out) {
    __shared__ float ht[4][WJ];
    __shared__ int jrow[WJ];
    __shared__ __align__(16) float gpart[4][4][256];
    __shared__ float hqred[4][4];
    __shared__ float hsred[4][4];
    int t = threadIdx.x;
    int bx = blockIdx.x;

    if (t < 64) out[bx * 64 + t] = 0x7f800000u;  // +inf (256*64 = 16384)

    int i0 = bx * 4;
    int r0 = i0 >> 5, c0 = i0 & 31;

    for (int u = t; u < WJ; u += 256) {
        int jr = (r0 + (u / WCc) - 6 + 32) & 31;
        int jc = (c0 + (u % WCc) - 7 + 32) & 31;
        int j = jr * 32 + jc;
        jrow[u] = j;
#pragma unroll
        for (int s = 0; s < 4; ++s) ht[s][u] = hval(i0 + s, j);
    }
    __syncthreads();

    int w = t >> 6, lane = t & 63;
    int j0 = w * JSUB;
    int j1 = (j0 + JSUB < WJ) ? j0 + JSUB : WJ;
    f32x4 g[4] = {{0.f, 0.f, 0.f, 0.f}, {0.f, 0.f, 0.f, 0.f},
                  {0.f, 0.f, 0.f, 0.f}, {0.f, 0.f, 0.f, 0.f}};
    float hqp[4] = {0.f, 0.f, 0.f, 0.f};
    float hsp[4] = {0.f, 0.f, 0.f, 0.f};
    for (int u = j0; u < j1; ++u) {
        f32x4 pv = *reinterpret_cast<const f32x4*>(P + (size_t)jrow[u] * D + lane * 4);
        float q = pv[0] * pv[0] + pv[1] * pv[1] + pv[2] * pv[2] + pv[3] * pv[3];
#pragma unroll
        for (int s = 0; s < 4; ++s) {
            float h = ht[s][u];
            g[s][0] = fmaf(h, pv[0], g[s][0]);
            g[s][1] = fmaf(h, pv[1], g[s][1]);
            g[s][2] = fmaf(h, pv[2], g[s][2]);
            g[s][3] = fmaf(h, pv[3], g[s][3]);
            hqp[s] = fmaf(h, q, hqp[s]);
            hsp[s] += h;  // lane-uniform
        }
    }
#pragma unroll
    for (int s = 0; s < 4; ++s)
        *reinterpret_cast<f32x4*>(&gpart[w][s][lane * 4]) = g[s];
#pragma unroll
    for (int s = 0; s < 4; ++s) {
#pragma unroll
        for (int off = 1; off < 64; off <<= 1) hqp[s] += __shfl_xor(hqp[s], off);
    }
    if (lane == 0) {
#pragma unroll
        for (int s = 0; s < 4; ++s) { hqred[w][s] = hqp[s]; hsred[w][s] = hsp[s]; }
    }
    __syncthreads();

    {
        int s = t >> 6;
        f32x4 gs = *reinterpret_cast<const f32x4*>(&gpart[0][s][lane * 4]);
#pragma unroll
        for (int ww = 1; ww < 4; ++ww) {
            f32x4 gp = *reinterpret_cast<const f32x4*>(&gpart[ww][s][lane * 4]);
            gs[0] += gp[0]; gs[1] += gp[1]; gs[2] += gp[2]; gs[3] += gp[3];
        }
        float h0 = __shfl_down(gs[0], 1);
        float h1 = __shfl_down(gs[1], 1);
        float h2 = __shfl_down(gs[2], 1);
        float h3 = __shfl_down(gs[3], 1);
        if (!(lane & 1)) {
            int c = lane >> 1;   // 16B chunk: k = c*8..+7
            int kt = c >> 2;
            int slot = c & 3;
            int i = i0 + s;
            int key = (i & 3) ^ ((i >> 2) & 3);
            short8 wv;
            wv[0] = f2bf(gs[0]); wv[1] = f2bf(gs[1]); wv[2] = f2bf(gs[2]); wv[3] = f2bf(gs[3]);
            wv[4] = f2bf(h0);    wv[5] = f2bf(h1);    wv[6] = f2bf(h2);    wv[7] = f2bf(h3);
            *reinterpret_cast<short8*>(
                GbS + (size_t)kt * (NPROTO * 32) + (size_t)i * 32 +
                ((slot ^ key) << 3)) = wv;
        }
    }
    if (t < 4) {
        hsum[i0 + t] = hsred[0][t] + hsred[1][t] + hsred[2][t] + hsred[3][t];
    } else if (t < 8) {
        int s = t - 4;
        hp2[i0 + s] = hqred[0][s] + hqred[1][s] + hqred[2][s] + hqred[3][s];
    }
}

// ---- som12: X read DIRECTLY (f32, reg-staged -> swizzled LDS; cvt at frag
//      read; x2 accumulated during staging). G via gload_lds from GbS.
//      Tile 128n x 128i, BK=32, 8 phases, issue-early/write-late + syncthreads
//      (only 2 long-issued G loads drain at the barrier). LDS 51KB. ----
__global__ void __launch_bounds__(256, 2) som12_kernel(
    const float* __restrict__ X, const short* __restrict__ GbS,
    const float* __restrict__ hsum, const float* __restrict__ hp2,
    unsigned* __restrict__ out) {
    __shared__ __align__(16) float Xsf[2][128 * 32];  // 16KB each (f32)
    __shared__ __align__(16) short Gs[2][128 * 32];   // 8KB each (bf16)
    __shared__ float x2s[128];
    __shared__ float red[2][128];

    const int t = threadIdx.x;
    const int lane = t & 63;
    const int wid = t >> 6;
    const int wr = wid >> 1;   // n half (64 rows)
    const int wc = wid & 1;    // i half (64 cols)
    const int lm = lane & 15;
    const int lq = lane >> 4;
    const int keyG = (lm & 3) ^ ((lm >> 2) & 3);
    const int k8 = lm & 7;     // X row swizzle key (row&7 == lm&7 for frag rows)

    // XCD-bijective swizzle: 1024 blocks = 8 XCDs x 128
    const int bx = blockIdx.x;
    const int w1024 = ((bx & 7) << 7) | (bx >> 3);
    const int n0 = (w1024 >> 3) * 128;
    const int ib0 = (w1024 & 7) * 128;

    // staging geometry: thread owns row srow = t>>1, half sh_ = t&1 (16 f32)
    const int srow = t >> 1;
    const int sh_ = t & 1;
    const int skey = srow & 7;

    f32x4 acc[4][4];
#pragma unroll
    for (int m = 0; m < 4; ++m)
#pragma unroll
        for (int n = 0; n < 4; ++n) acc[m][n] = (f32x4){0.f, 0.f, 0.f, 0.f};

    float sq = 0.f;
    f32x4 xr0, xr1, xr2, xr3;

    auto issueX = [&](int kt) {
        const f32x4* src = reinterpret_cast<const f32x4*>(
            X + (size_t)(n0 + srow) * D + kt * 32 + sh_ * 16);
        xr0 = src[0]; xr1 = src[1]; xr2 = src[2]; xr3 = src[3];
    };
    auto issueG = [&](int b, int kt) {
#pragma unroll
        for (int q = 0; q < 2; ++q)
            gload_lds16((char*)(&Gs[b][0]) + q * 4096 + t * 16,
                        GbS + (size_t)kt * (NPROTO * 32) +
                        (size_t)(ib0 + q * 64 + (t >> 2)) * 32 + ((t & 3) << 3));
    };
    auto writeX = [&](int b) {
        char* base = (char*)(&Xsf[b][0]) + srow * 128;
        *reinterpret_cast<f32x4*>(base + (((sh_ * 4 + 0) ^ skey) << 4)) = xr0;
        *reinterpret_cast<f32x4*>(base + (((sh_ * 4 + 1) ^ skey) << 4)) = xr1;
        *reinterpret_cast<f32x4*>(base + (((sh_ * 4 + 2) ^ skey) << 4)) = xr2;
        *reinterpret_cast<f32x4*>(base + (((sh_ * 4 + 3) ^ skey) << 4)) = xr3;
        sq += xr0[0] * xr0[0] + xr0[1] * xr0[1] + xr0[2] * xr0[2] + xr0[3] * xr0[3] +
              xr1[0] * xr1[0] + xr1[1] * xr1[1] + xr1[2] * xr1[2] + xr1[3] * xr1[3] +
              xr2[0] * xr2[0] + xr2[1] * xr2[1] + xr2[2] * xr2[2] + xr2[3] * xr2[3] +
              xr3[0] * xr3[0] + xr3[1] * xr3[1] + xr3[2] * xr3[2] + xr3[3] * xr3[3];
    };

    auto compute = [&](int b) {
        const char* xbase = (const char*)(&Xsf[b][0]);
        const short* gb = &Gs[b][0];
        short8 a[4];
#pragma unroll
        for (int m = 0; m < 4; ++m) {
            int row = wr * 64 + m * 16 + lm;
            const char* rb = xbase + row * 128;
            f32x4 lo = *reinterpret_cast<const f32x4*>(rb + ((((lq * 2) + 0) ^ k8) << 4));
            f32x4 hi = *reinterpret_cast<const f32x4*>(rb + ((((lq * 2) + 1) ^ k8) << 4));
            short8 av;
            av[0] = f2bf(lo[0]); av[1] = f2bf(lo[1]); av[2] = f2bf(lo[2]); av[3] = f2bf(lo[3]);
            av[4] = f2bf(hi[0]); av[5] = f2bf(hi[1]); av[6] = f2bf(hi[2]); av[7] = f2bf(hi[3]);
            a[m] = av;
        }
        short8 b_[4];
#pragma unroll
        for (int n = 0; n < 4; ++n)
            b_[n] = *reinterpret_cast<const short8*>(
                &gb[(wc * 64 + n * 16 + lm) * 32 + ((lq ^ keyG) << 3)]);
        __builtin_amdgcn_s_setprio(1);
#pragma unroll
        for (int m = 0; m < 4; ++m)
#pragma unroll
            for (int n = 0; n < 4; ++n)
                acc[m][n] = __builtin_amdgcn_mfma_f32_16x16x32_bf16(a[m], b_[n], acc[m][n], 0, 0, 0);
        __builtin_amdgcn_s_setprio(0);
    };

    // prologue: stage phase 0
    issueG(0, 0);
    issueX(0);
    writeX(0);
    __syncthreads();

#pragma unroll
    for (int kt = 0; kt < 8; ++kt) {
        if (kt < 7) {
            issueG((kt + 1) & 1, kt + 1);   // in flight across compute
            issueX(kt + 1);                 // into regs, consumed post-compute
        }
        compute(kt & 1);
        if (kt < 7) writeX((kt + 1) & 1);
        __syncthreads();                    // drains 2 G-loads (latency hidden)
    }

    // ---- x2 from staged sums: row = t>>1 owned by 2 threads (halves) ----
    if (sh_ == 0) x2s[srow] = sq;
    __syncthreads();
    if (sh_ == 1) x2s[srow] += sq;
    __syncthreads();

    // ---- epilogue: e = hsum*x2 + hp2 - 2*acc; min over block's 128 i ----
    float x2v[4][4];
#pragma unroll
    for (int m = 0; m < 4; ++m)
#pragma unroll
        for (int j = 0; j < 4; ++j)
            x2v[m][j] = x2s[wr * 64 + m * 16 + lq * 4 + j];

    float rmin[4][4];
#pragma unroll
    for (int m = 0; m < 4; ++m)
#pragma unroll
        for (int j = 0; j < 4; ++j) rmin[m][j] = 3.4e38f;

#pragma unroll
    for (int ni = 0; ni < 4; ++ni) {
        int ig = ib0 + wc * 64 + ni * 16 + lm;
        float hs = hsum[ig];
        float hq = hp2[ig];
#pragma unroll
        for (int m = 0; m < 4; ++m)
#pragma unroll
            for (int j = 0; j < 4; ++j) {
                float e = fmaf(hs, x2v[m][j], hq) - 2.0f * acc[m][ni][j];
                rmin[m][j] = fminf(rmin[m][j], e);
            }
    }

#pragma unroll
    for (int m = 0; m < 4; ++m)
#pragma unroll
        for (int j = 0; j < 4; ++j) {
            float v = rmin[m][j];
            v = fminf(v, __shfl_xor(v, 1));
            v = fminf(v, __shfl_xor(v, 2));
            v = fminf(v, __shfl_xor(v, 4));
            v = fminf(v, __shfl_xor(v, 8));
            rmin[m][j] = v;
        }
    if (lm == 0) {
#pragma unroll
        for (int m = 0; m < 4; ++m)
#pragma unroll
            for (int j = 0; j < 4; ++j)
                red[wc][wr * 64 + m * 16 + lq * 4 + j] = rmin[m][j];
    }
    __syncthreads();
    if (t < 128) {
        float v = fminf(red[0][t], red[1][t]);
        atomicMin(out + n0 + t, __float_as_uint(0.5f * v));
    }
}

extern "C" void kernel_launch(void* const* d_in, const int* in_sizes, int n_in,
                              void* d_out, int out_size, void* d_ws, size_t ws_size,
                              hipStream_t stream) {
    const float* X = (const float*)d_in[0];  // [16384, 256]
    const float* P = (const float*)d_in[1];  // [1024, 256]
    unsigned* out = (unsigned*)d_out;        // [1, 16384] f32 as uint
    (void)in_sizes; (void)n_in; (void)out_size; (void)ws_size;

    float* ws = (float*)d_ws;
    float* hsum = ws + 1024;             // 1024 f32
    float* hp2 = ws + 2048;              // 1024 f32
    short* GbS = (short*)(ws + 32768);   // 1024*256 bf16 kt-major swizzled (512KB)

    prep_kernel<<<GMAT_BLOCKS, 256, 0, stream>>>(P, GbS, hsum, hp2, out);
    som12_kernel<<<1024, 256, 0, stream>>>(X, GbS, hsum, hp2, out);
}

// Round 13
// 31.429 us; speedup vs baseline: 1.1752x; 1.1752x over previous
//
#include <hip/hip_runtime.h>
#include <hip/hip_bf16.h>
#include <math.h>

#define D 256
#define NPROTO 1024
#define NROWS 16384
#define WRr 13
#define WCc 18
#define WJ (WRr * WCc)
#define JSUB 59                    // ceil(WJ/4)
#define GMAT_BLOCKS (NPROTO / 4)   // 256
#define XPREP_BLOCKS (NROWS / 32)  // 512

#define WAITVM(N) asm volatile("s_waitcnt vmcnt(" #N ")" ::: "memory")

typedef __attribute__((ext_vector_type(8))) short short8;
typedef __attribute__((ext_vector_type(4))) float f32x4;

// slot-swizzle key for 64-byte rows (4 slots of 16B); same key on ws write
// and LDS read (rule 21). 2-way max bank aliasing (free, m136).
__device__ __forceinline__ int swz_key(int row) {
    return (row & 3) ^ ((row >> 2) & 3);
}

__device__ __forceinline__ short f2bf(float f) {
    union { __hip_bfloat16 b; short s; } u;
    u.b = __float2bfloat16(f);
    return u.s;
}

__device__ __forceinline__ void gload_lds16(void* lds, const void* g) {
    __builtin_amdgcn_global_load_lds(
        (const __attribute__((address_space(1))) unsigned*)g,
        (__attribute__((address_space(3))) unsigned*)lds, 16, 0, 0);
}

// ---- hex-grid neighborhood H[i,j], fp32 (abs err ~1e-6 on h; energies need
//      only ~1e-1 — fp64 exp removed from gmat's critical path) ----
__device__ __forceinline__ float hval(int i, int j) {
    int ri = i >> 5, ci = i & 31;
    int rj = j >> 5, cj = j & 31;
    float xi = (float)ci + 0.5f * (float)(ri & 1);
    float yi = (float)ri * 0.86602540f;
    float xj = (float)cj + 0.5f * (float)(rj & 1);
    float yj = (float)rj * 0.86602540f;
    float dx0 = xi - xj, dy0 = yi - yj;
    const float W = 32.0f;
    const float Hh = 27.7128129f;  // 32*sqrt(3)/2
    float best = 3.4e38f;
#pragma unroll
    for (int sx = -1; sx <= 1; ++sx) {
        float dx = dx0 + (float)sx * W;
#pragma unroll
        for (int sy = -1; sy <= 1; ++sy) {
            float dy = dy0 + (float)sy * Hh;
            float d2 = dx * dx + dy * dy;
            best = fminf(best, d2);
        }
    }
    return __expf(-0.5f * best);
}

// ws layouts (kt-major, slot-swizzled), k = kt*32 + slot*8 + e:
//  XgS short idx = kt*(NROWS*32) + row*32 + ((slot ^ key(row))*8) + e
//  GbS short idx = kt*(NPROTO*32) + i*32  + ((slot ^ key(i))*8) + e

// ---- prep: role-split.
//  bx < 256:   gmat -> GbS + hsum + hp2  (sparse 13x18 torus window, j-split)
//  bx >= 256:  xprep -> XgS + x2 + out=+inf, XCD-ALIGNED: block xb (XCD=xb%8)
//              writes rows [2048*(xb%8) + 32*(xb/8), +32) — the exact slice
//              som's XCD-(xb%8) blocks consume -> producer/consumer same L2.
__global__ void __launch_bounds__(256) prep_kernel(
    const float* __restrict__ X, const float* __restrict__ P,
    short* __restrict__ XgS, short* __restrict__ GbS,
    float* __restrict__ x2, float* __restrict__ hsum, float* __restrict__ hp2,
    unsigned* __restrict__ out) {
    int t = threadIdx.x;
    int bx = blockIdx.x;

    if (bx >= GMAT_BLOCKS) {
        // ---------------- xprep: 32 rows, XCD-aligned base ----------------
        int xb = bx - GMAT_BLOCKS;
        int base0 = (xb & 7) * 2048 + (xb >> 3) * 32;
        int g = t & 31;          // k-chunk: k = g*8..+7
        int kt = g >> 2;
        int slot = g & 3;
#pragma unroll
        for (int it = 0; it < 4; ++it) {
            int row = base0 + it * 8 + (t >> 5);
            const float4* src = reinterpret_cast<const float4*>(X + (size_t)row * D) + g * 2;
            float4 a = src[0], b = src[1];
            float s = a.x * a.x + a.y * a.y + a.z * a.z + a.w * a.w +
                      b.x * b.x + b.y * b.y + b.z * b.z + b.w * b.w;
            s += __shfl_xor(s, 1);
            s += __shfl_xor(s, 2);
            s += __shfl_xor(s, 4);
            s += __shfl_xor(s, 8);
            s += __shfl_xor(s, 16);
            if (g == 0) x2[row] = s;
            short8 w;
            w[0] = f2bf(a.x); w[1] = f2bf(a.y); w[2] = f2bf(a.z); w[3] = f2bf(a.w);
            w[4] = f2bf(b.x); w[5] = f2bf(b.y); w[6] = f2bf(b.z); w[7] = f2bf(b.w);
            *reinterpret_cast<short8*>(
                XgS + (size_t)kt * (NROWS * 32) + (size_t)row * 32 +
                ((slot ^ swz_key(row)) << 3)) = w;
        }
        if (t < 32) out[base0 + t] = 0x7f800000u;  // +inf
        return;
    }

    // ---------------- gmat ----------------
    __shared__ float ht[4][WJ];
    __shared__ int jrow[WJ];
    __shared__ __align__(16) float gpart[4][4][256];
    __shared__ float hqred[4][4];
    __shared__ float hsred[4][4];
    int i0 = bx * 4;
    int r0 = i0 >> 5, c0 = i0 & 31;

    for (int u = t; u < WJ; u += 256) {
        int jr = (r0 + (u / WCc) - 6 + 32) & 31;
        int jc = (c0 + (u % WCc) - 7 + 32) & 31;
        int j = jr * 32 + jc;
        jrow[u] = j;
#pragma unroll
        for (int s = 0; s < 4; ++s) ht[s][u] = hval(i0 + s, j);
    }
    __syncthreads();

    int w = t >> 6, lane = t & 63;
    int j0 = w * JSUB;
    int j1 = (j0 + JSUB < WJ) ? j0 + JSUB : WJ;
    f32x4 g[4] = {{0.f, 0.f, 0.f, 0.f}, {0.f, 0.f, 0.f, 0.f},
                  {0.f, 0.f, 0.f, 0.f}, {0.f, 0.f, 0.f, 0.f}};
    float hqp[4] = {0.f, 0.f, 0.f, 0.f};
    float hsp[4] = {0.f, 0.f, 0.f, 0.f};
    for (int u = j0; u < j1; ++u) {
        f32x4 pv = *reinterpret_cast<const f32x4*>(P + (size_t)jrow[u] * D + lane * 4);
        float q = pv[0] * pv[0] + pv[1] * pv[1] + pv[2] * pv[2] + pv[3] * pv[3];
#pragma unroll
        for (int s = 0; s < 4; ++s) {
            float h = ht[s][u];
            g[s][0] = fmaf(h, pv[0], g[s][0]);
            g[s][1] = fmaf(h, pv[1], g[s][1]);
            g[s][2] = fmaf(h, pv[2], g[s][2]);
            g[s][3] = fmaf(h, pv[3], g[s][3]);
            hqp[s] = fmaf(h, q, hqp[s]);
            hsp[s] += h;  // lane-uniform
        }
    }
#pragma unroll
    for (int s = 0; s < 4; ++s)
        *reinterpret_cast<f32x4*>(&gpart[w][s][lane * 4]) = g[s];
#pragma unroll
    for (int s = 0; s < 4; ++s) {
#pragma unroll
        for (int off = 1; off < 64; off <<= 1) hqp[s] += __shfl_xor(hqp[s], off);
    }
    if (lane == 0) {
#pragma unroll
        for (int s = 0; s < 4; ++s) { hqred[w][s] = hqp[s]; hsred[w][s] = hsp[s]; }
    }
    __syncthreads();

    {
        int s = t >> 6;
        f32x4 gs = *reinterpret_cast<const f32x4*>(&gpart[0][s][lane * 4]);
#pragma unroll
        for (int ww = 1; ww < 4; ++ww) {
            f32x4 gp = *reinterpret_cast<const f32x4*>(&gpart[ww][s][lane * 4]);
            gs[0] += gp[0]; gs[1] += gp[1]; gs[2] += gp[2]; gs[3] += gp[3];
        }
        float h0 = __shfl_down(gs[0], 1);
        float h1 = __shfl_down(gs[1], 1);
        float h2 = __shfl_down(gs[2], 1);
        float h3 = __shfl_down(gs[3], 1);
        if (!(lane & 1)) {
            int c = lane >> 1;   // 16B chunk: k = c*8..+7
            int kt = c >> 2;
            int slot = c & 3;
            int i = i0 + s;
            short8 wv;
            wv[0] = f2bf(gs[0]); wv[1] = f2bf(gs[1]); wv[2] = f2bf(gs[2]); wv[3] = f2bf(gs[3]);
            wv[4] = f2bf(h0);    wv[5] = f2bf(h1);    wv[6] = f2bf(h2);    wv[7] = f2bf(h3);
            *reinterpret_cast<short8*>(
                GbS + (size_t)kt * (NPROTO * 32) + (size_t)i * 32 +
                ((slot ^ swz_key(i)) << 3)) = wv;
        }
    }
    if (t < 4) {
        hsum[i0 + t] = hsred[0][t] + hsred[1][t] + hsred[2][t] + hsred[3][t];
    } else if (t < 8) {
        int s = t - 4;
        hp2[i0 + s] = hqred[0][s] + hqred[1][s] + hqred[2][s] + hqred[3][s];
    }
}

// ---- som8 (R10 verbatim): 128n x 128i tile, BK=32, 8 phases, dbuf 32KB LDS
//      -> 4 blocks/CU. Counted vmcnt(4), XCD-bijective swizzle. ----
__global__ void __launch_bounds__(256, 4) som8_kernel(
    const short* __restrict__ XgS, const short* __restrict__ GbS,
    const float* __restrict__ x2, const float* __restrict__ hsum,
    const float* __restrict__ hp2, unsigned* __restrict__ out) {
    __shared__ __align__(16) short Xs[2][128 * 32];  // 8KB each
    __shared__ __align__(16) short Gs[2][128 * 32];
    __shared__ float red[2][128];

    const int t = threadIdx.x;
    const int lane = t & 63;
    const int wid = t >> 6;
    const int wr = wid >> 1;   // n half (64 rows)
    const int wc = wid & 1;    // i half (64 cols)
    const int lm = lane & 15;
    const int lq = lane >> 4;
    const int key = (lm & 3) ^ ((lm >> 2) & 3);

    // XCD-bijective swizzle: 1024 blocks = 8 XCDs x 128; XCD k covers
    // nb in [16k,16k+16) x all 8 ib -> 1MB XgS + 512KB GbS per XCD L2.
    const int lin = blockIdx.x;
    const int w1024 = ((lin & 7) << 7) | (lin >> 3);
    const int n0 = (w1024 >> 3) * 128;
    const int ib0 = (w1024 & 7) * 128;

    f32x4 acc[4][4];
#pragma unroll
    for (int m = 0; m < 4; ++m)
#pragma unroll
        for (int n = 0; n < 4; ++n) acc[m][n] = (f32x4){0.f, 0.f, 0.f, 0.f};

    auto stage = [&](int b, int kt) {
        // linear dest; sources pre-swizzled in ws -> contiguous reads
#pragma unroll
        for (int q = 0; q < 2; ++q)
            gload_lds16((char*)(&Xs[b][0]) + q * 4096 + t * 16,
                        XgS + (size_t)kt * (NROWS * 32) +
                        (size_t)(n0 + q * 64 + (t >> 2)) * 32 + ((t & 3) << 3));
#pragma unroll
        for (int q = 0; q < 2; ++q)
            gload_lds16((char*)(&Gs[b][0]) + q * 4096 + t * 16,
                        GbS + (size_t)kt * (NPROTO * 32) +
                        (size_t)(ib0 + q * 64 + (t >> 2)) * 32 + ((t & 3) << 3));
    };

    stage(0, 0);  // 4 VMEM outstanding

#pragma unroll
    for (int p = 0; p < 8; ++p) {
        if (p < 7) stage((p + 1) & 1, p + 1);          // +4 -> 8 outstanding
        if (p < 7) { WAITVM(4); } else { WAITVM(0); }  // retire phase-p stage
        __builtin_amdgcn_sched_barrier(0);
        __builtin_amdgcn_s_barrier();

        const short* xb = &Xs[p & 1][0];
        const short* gb = &Gs[p & 1][0];
        const int so = (lq ^ key) << 3;
        short8 a[4], b[4];
#pragma unroll
        for (int m = 0; m < 4; ++m)
            a[m] = *reinterpret_cast<const short8*>(&xb[(wr * 64 + m * 16 + lm) * 32 + so]);
#pragma unroll
        for (int n = 0; n < 4; ++n)
            b[n] = *reinterpret_cast<const short8*>(&gb[(wc * 64 + n * 16 + lm) * 32 + so]);
        __builtin_amdgcn_s_setprio(1);
#pragma unroll
        for (int m = 0; m < 4; ++m)
#pragma unroll
            for (int n = 0; n < 4; ++n)
                acc[m][n] = __builtin_amdgcn_mfma_f32_16x16x32_bf16(a[m], b[n], acc[m][n], 0, 0, 0);
        __builtin_amdgcn_s_setprio(0);
        __builtin_amdgcn_s_barrier();
    }

    // ---- epilogue: e = hsum*x2 + hp2 - 2*acc; min over block's 128 i ----
    float x2v[4][4];
#pragma unroll
    for (int m = 0; m < 4; ++m)
#pragma unroll
        for (int j = 0; j < 4; ++j)
            x2v[m][j] = x2[n0 + wr * 64 + m * 16 + lq * 4 + j];

    float rmin[4][4];
#pragma unroll
    for (int m = 0; m < 4; ++m)
#pragma unroll
        for (int j = 0; j < 4; ++j) rmin[m][j] = 3.4e38f;

#pragma unroll
    for (int ni = 0; ni < 4; ++ni) {
        int ig = ib0 + wc * 64 + ni * 16 + lm;
        float hs = hsum[ig];
        float hq = hp2[ig];
#pragma unroll
        for (int m = 0; m < 4; ++m)
#pragma unroll
            for (int j = 0; j < 4; ++j) {
                float e = fmaf(hs, x2v[m][j], hq) - 2.0f * acc[m][ni][j];
                rmin[m][j] = fminf(rmin[m][j], e);
            }
    }

#pragma unroll
    for (int m = 0; m < 4; ++m)
#pragma unroll
        for (int j = 0; j < 4; ++j) {
            float v = rmin[m][j];
            v = fminf(v, __shfl_xor(v, 1));
            v = fminf(v, __shfl_xor(v, 2));
            v = fminf(v, __shfl_xor(v, 4));
            v = fminf(v, __shfl_xor(v, 8));
            rmin[m][j] = v;
        }
    if (lm == 0) {
#pragma unroll
        for (int m = 0; m < 4; ++m)
#pragma unroll
            for (int j = 0; j < 4; ++j)
                red[wc][wr * 64 + m * 16 + lq * 4 + j] = rmin[m][j];
    }
    __syncthreads();
    if (t < 128) {
        float v = fminf(red[0][t], red[1][t]);
        atomicMin(out + n0 + t, __float_as_uint(0.5f * v));
    }
}

extern "C" void kernel_launch(void* const* d_in, const int* in_sizes, int n_in,
                              void* d_out, int out_size, void* d_ws, size_t ws_size,
                              hipStream_t stream) {
    const float* X = (const float*)d_in[0];  // [16384, 256]
    const float* P = (const float*)d_in[1];  // [1024, 256]
    unsigned* out = (unsigned*)d_out;        // [1, 16384] f32 as uint
    (void)in_sizes; (void)n_in; (void)out_size; (void)ws_size;

    float* ws = (float*)d_ws;
    float* hsum = ws + 1024;             // 1024 f32
    float* hp2 = ws + 2048;              // 1024 f32
    float* x2 = ws + 4096;               // 16384 f32
    short* GbS = (short*)(ws + 32768);   // 1024*256 bf16 kt-major swizzled (512KB)
    short* XgS = (short*)(ws + 262144);  // 16384*256 bf16 kt-major swizzled (8.4MB)

    prep_kernel<<<GMAT_BLOCKS + XPREP_BLOCKS, 256, 0, stream>>>(
        X, P, XgS, GbS, x2, hsum, hp2, out);
    som8_kernel<<<1024, 256, 0, stream>>>(XgS, GbS, x2, hsum, hp2, out);
}